// Round 1
// baseline (333.037 us; speedup 1.0000x reference)
//
#include <hip/hip_runtime.h>

// Squared Euclidean distance matrix: out[n][m] = ||x1[n] - x2[m]||^2
//  = sq1[n] + sq2[m] - 2 * dot(x1[n], x2[m]),  clamped at 0.
// N = M = 8192, K = 64, fp32. Output 256 MB.
//
// Structure: 128x128 output tile per 256-thread block, 8x8 register tile per
// thread. LDS holds both input tiles k-major ([K][132], +4 pad keeps 16B
// alignment for ds_read_b128 while spreading banks). fp32 vector FMA
// (no fp32 MFMA on CDNA4) -> VALU-bound ~55us floor; HBM write floor ~41us.

#define TILE 128
#define KDIM 64
#define LDS_STRIDE 132   // floats; 132*4=528 B, 16B-aligned rows, banks spread

__global__ __launch_bounds__(256, 2)
void sqeuclid_kernel(const float* __restrict__ x1,
                     const float* __restrict__ x2,
                     float* __restrict__ out,
                     int N, int M) {
    __shared__ float a_s[KDIM][LDS_STRIDE];   // a_s[k][m], m = local row of x1 tile
    __shared__ float b_s[KDIM][LDS_STRIDE];   // b_s[k][n], n = local col (x2 row)
    __shared__ float sq1_s[TILE];
    __shared__ float sq2_s[TILE];

    const int t = threadIdx.x;                 // 0..255
    const int block_row = blockIdx.y * TILE;   // into x1 / out rows
    const int block_col = blockIdx.x * TILE;   // into x2 / out cols

    // ---- Stage global -> LDS with in-register 4x4 transpose (row-major ->
    // k-major). Item = (kv, rg): k-quad kv in [0,16), row-group rg in [0,32).
    // kv = t&15 keeps global loads coalesced (16 lanes read one row's 256 B).
    {
        const int kv = t & 15;
        #pragma unroll
        for (int it = 0; it < 2; ++it) {
            const int rg = (t >> 4) + it * 16;
            const int r  = rg * 4;
            const float4 a0 = *(const float4*)(x1 + (size_t)(block_row + r + 0) * KDIM + kv * 4);
            const float4 a1 = *(const float4*)(x1 + (size_t)(block_row + r + 1) * KDIM + kv * 4);
            const float4 a2 = *(const float4*)(x1 + (size_t)(block_row + r + 2) * KDIM + kv * 4);
            const float4 a3 = *(const float4*)(x1 + (size_t)(block_row + r + 3) * KDIM + kv * 4);
            *(float4*)&a_s[kv * 4 + 0][r] = make_float4(a0.x, a1.x, a2.x, a3.x);
            *(float4*)&a_s[kv * 4 + 1][r] = make_float4(a0.y, a1.y, a2.y, a3.y);
            *(float4*)&a_s[kv * 4 + 2][r] = make_float4(a0.z, a1.z, a2.z, a3.z);
            *(float4*)&a_s[kv * 4 + 3][r] = make_float4(a0.w, a1.w, a2.w, a3.w);

            const float4 b0 = *(const float4*)(x2 + (size_t)(block_col + r + 0) * KDIM + kv * 4);
            const float4 b1 = *(const float4*)(x2 + (size_t)(block_col + r + 1) * KDIM + kv * 4);
            const float4 b2 = *(const float4*)(x2 + (size_t)(block_col + r + 2) * KDIM + kv * 4);
            const float4 b3 = *(const float4*)(x2 + (size_t)(block_col + r + 3) * KDIM + kv * 4);
            *(float4*)&b_s[kv * 4 + 0][r] = make_float4(b0.x, b1.x, b2.x, b3.x);
            *(float4*)&b_s[kv * 4 + 1][r] = make_float4(b0.y, b1.y, b2.y, b3.y);
            *(float4*)&b_s[kv * 4 + 2][r] = make_float4(b0.z, b1.z, b2.z, b3.z);
            *(float4*)&b_s[kv * 4 + 3][r] = make_float4(b0.w, b1.w, b2.w, b3.w);
        }
    }
    __syncthreads();

    // ---- Cooperative row/col norms (once per block, ~1.5% of main loop).
    if (t < TILE) {
        float s = 0.f;
        #pragma unroll 8
        for (int k = 0; k < KDIM; ++k) { const float v = a_s[k][t]; s = fmaf(v, v, s); }
        sq1_s[t] = s;
    } else {
        const int m = t - TILE;
        float s = 0.f;
        #pragma unroll 8
        for (int k = 0; k < KDIM; ++k) { const float v = b_s[k][m]; s = fmaf(v, v, s); }
        sq2_s[m] = s;
    }
    __syncthreads();

    // ---- Main loop: 8x8 accumulator per thread. Wave lane map 8x8 so both
    // LDS fragment reads are only 2-way bank-aliased (free on gfx950).
    const int wave = t >> 6;
    const int lane = t & 63;
    const int row0 = (wave >> 1) * 64 + (lane >> 3) * 8;  // local row base
    const int col0 = (wave & 1) * 64 + (lane & 7) * 8;    // local col base

    float acc[8][8];
    #pragma unroll
    for (int i = 0; i < 8; ++i)
        #pragma unroll
        for (int j = 0; j < 8; ++j) acc[i][j] = 0.f;

    for (int k = 0; k < KDIM; ++k) {
        const float4 aA = *(const float4*)&a_s[k][row0];
        const float4 aB = *(const float4*)&a_s[k][row0 + 4];
        const float4 bA = *(const float4*)&b_s[k][col0];
        const float4 bB = *(const float4*)&b_s[k][col0 + 4];
        const float ar[8] = {aA.x, aA.y, aA.z, aA.w, aB.x, aB.y, aB.z, aB.w};
        const float br[8] = {bA.x, bA.y, bA.z, bA.w, bB.x, bB.y, bB.z, bB.w};
        #pragma unroll
        for (int i = 0; i < 8; ++i)
            #pragma unroll
            for (int j = 0; j < 8; ++j)
                acc[i][j] = fmaf(ar[i], br[j], acc[i][j]);
    }

    // ---- Epilogue: d2 = sq1 + sq2 - 2*dot, clamp >= 0, float4 stores.
    #pragma unroll
    for (int i = 0; i < 8; ++i) {
        const size_t gr = (size_t)(block_row + row0 + i) * M + block_col + col0;
        const float s1 = sq1_s[row0 + i];
        float4 o0, o1;
        o0.x = fmaxf(fmaf(-2.f, acc[i][0], s1 + sq2_s[col0 + 0]), 0.f);
        o0.y = fmaxf(fmaf(-2.f, acc[i][1], s1 + sq2_s[col0 + 1]), 0.f);
        o0.z = fmaxf(fmaf(-2.f, acc[i][2], s1 + sq2_s[col0 + 2]), 0.f);
        o0.w = fmaxf(fmaf(-2.f, acc[i][3], s1 + sq2_s[col0 + 3]), 0.f);
        o1.x = fmaxf(fmaf(-2.f, acc[i][4], s1 + sq2_s[col0 + 4]), 0.f);
        o1.y = fmaxf(fmaf(-2.f, acc[i][5], s1 + sq2_s[col0 + 5]), 0.f);
        o1.z = fmaxf(fmaf(-2.f, acc[i][6], s1 + sq2_s[col0 + 6]), 0.f);
        o1.w = fmaxf(fmaf(-2.f, acc[i][7], s1 + sq2_s[col0 + 7]), 0.f);
        *(float4*)(out + gr)     = o0;
        *(float4*)(out + gr + 4) = o1;
    }
}

extern "C" void kernel_launch(void* const* d_in, const int* in_sizes, int n_in,
                              void* d_out, int out_size, void* d_ws, size_t ws_size,
                              hipStream_t stream) {
    const float* x1 = (const float*)d_in[0];
    const float* x2 = (const float*)d_in[1];
    float* out = (float*)d_out;
    const int N = in_sizes[0] / KDIM;   // 8192
    const int M = in_sizes[1] / KDIM;   // 8192

    dim3 grid(M / TILE, N / TILE);      // (64, 64)
    dim3 block(256);
    sqeuclid_kernel<<<grid, block, 0, stream>>>(x1, x2, out, N, M);
}

// Round 2
// 278.138 us; speedup vs baseline: 1.1974x; 1.1974x over previous
//
#include <hip/hip_runtime.h>

// Squared Euclidean distance matrix: out[n][m] = sq1[n] + sq2[m] - 2*dot(x1[n],x2[m]), clamped >= 0.
// N = M = 8192, K = 64, fp32 in/out. Output 256 MB -> HBM-write-bound floor ~41us.
// Cross term via bf16 MFMA (16x16x32); norms kept fp32 exact. Error budget:
// 2*|dot_fp32 - dot_bf16| ~ O(1) << 5.88 threshold.
//
// Per block: 128x128 out tile, 256 threads (4 waves), each wave a 64x64 quadrant
// = 4x4 MFMA tiles, K=64 = 2 k-steps. LDS bf16 tiles row-major, stride 72 ushort
// (+16B pad) -> fragment ds_read_b128 conflict-free (even 8 words/bank).

typedef __bf16 bf16x8 __attribute__((ext_vector_type(8)));
typedef float floatx4 __attribute__((ext_vector_type(4)));
typedef unsigned short ushort8 __attribute__((ext_vector_type(8)));

#define TILE 128
#define KD 64
#define LDSS 72   // ushort per row: 64 data + 8 pad (16 B); row = 144 B, 16B-aligned

__device__ __forceinline__ unsigned short f2bf(float x) {
    // round-to-nearest-even fp32 -> bf16 (finite inputs only)
    union { float f; unsigned int u; } v; v.f = x;
    return (unsigned short)((v.u + 0x7FFFu + ((v.u >> 16) & 1u)) >> 16);
}

__global__ void sqeuclid_mfma(const float* __restrict__ x1,
                              const float* __restrict__ x2,
                              float* __restrict__ out,
                              int M) {
    __shared__ unsigned short a_s[TILE][LDSS];   // bf16 bits of x1 tile [row][k]
    __shared__ unsigned short b_s[TILE][LDSS];   // bf16 bits of x2 tile [row][k]
    __shared__ float sq1_s[TILE];
    __shared__ float sq2_s[TILE];

    const int t = threadIdx.x;                 // 0..255
    const int block_row = blockIdx.y * TILE;
    const int block_col = blockIdx.x * TILE;

    // ---- Stage fp32 -> bf16 into LDS; fp32 row norms on the side.
    // Thread t stages one full row: matrix = t>>7, local row = t&127.
    {
        const int r = t & 127;
        const float* src = (t < TILE) ? (x1 + (size_t)(block_row + r) * KD)
                                      : (x2 + (size_t)(block_col + r) * KD);
        unsigned short* dst = (t < TILE) ? a_s[r] : b_s[r];
        float nrm = 0.f;
        #pragma unroll
        for (int i = 0; i < 8; ++i) {          // 2 float4 -> 1 ushort8 (16B LDS write)
            const float4 f0 = ((const float4*)src)[2 * i];
            const float4 f1 = ((const float4*)src)[2 * i + 1];
            nrm = fmaf(f0.x, f0.x, nrm); nrm = fmaf(f0.y, f0.y, nrm);
            nrm = fmaf(f0.z, f0.z, nrm); nrm = fmaf(f0.w, f0.w, nrm);
            nrm = fmaf(f1.x, f1.x, nrm); nrm = fmaf(f1.y, f1.y, nrm);
            nrm = fmaf(f1.z, f1.z, nrm); nrm = fmaf(f1.w, f1.w, nrm);
            ushort8 pk;
            pk[0] = f2bf(f0.x); pk[1] = f2bf(f0.y); pk[2] = f2bf(f0.z); pk[3] = f2bf(f0.w);
            pk[4] = f2bf(f1.x); pk[5] = f2bf(f1.y); pk[6] = f2bf(f1.z); pk[7] = f2bf(f1.w);
            *(ushort8*)&dst[i * 8] = pk;       // bank = 4*(r+i) mod 32: even spread
        }
        if (t < TILE) sq1_s[r] = nrm; else sq2_s[r] = nrm;
    }
    __syncthreads();

    // ---- MFMA: wave quadrant (wr,wc), 4x4 tiles of 16x16, K = 2 steps of 32.
    // A-frag: A[m=lane&15][k=(lane>>4)*8+j]; B-frag: B[k=(lane>>4)*8+j][n=lane&15]
    // (both read 16 B along k from row lane&15 of their tile). D: col=lane&15,
    // row=(lane>>4)*4+reg  [m89/m91-verified layouts].
    const int wave = t >> 6, lane = t & 63;
    const int wr = (wave >> 1) * 64;           // quadrant row base
    const int wc = (wave & 1) * 64;            // quadrant col base
    const int lm = lane & 15, lq = lane >> 4;

    floatx4 acc[4][4];
    #pragma unroll
    for (int i = 0; i < 4; ++i)
        #pragma unroll
        for (int j = 0; j < 4; ++j)
            acc[i][j] = (floatx4){0.f, 0.f, 0.f, 0.f};

    #pragma unroll
    for (int ks = 0; ks < 2; ++ks) {
        const int koff = ks * 32 + lq * 8;     // bf16 elements; *2 bytes, 16B-aligned
        bf16x8 afr[4], bfr[4];
        #pragma unroll
        for (int i = 0; i < 4; ++i) {
            afr[i] = *(const bf16x8*)&a_s[wr + i * 16 + lm][koff];
            bfr[i] = *(const bf16x8*)&b_s[wc + i * 16 + lm][koff];
        }
        #pragma unroll
        for (int i = 0; i < 4; ++i)
            #pragma unroll
            for (int j = 0; j < 4; ++j)
                acc[i][j] = __builtin_amdgcn_mfma_f32_16x16x32_bf16(
                    afr[i], bfr[j], acc[i][j], 0, 0, 0);
    }

    // ---- Epilogue: d2 = sq1 + sq2 - 2*dot, clamp, dword stores
    // (16 lanes = 64 contiguous bytes per row-group -> dense lines).
    #pragma unroll
    for (int i = 0; i < 4; ++i) {
        #pragma unroll
        for (int r = 0; r < 4; ++r) {
            const int lrow = wr + i * 16 + lq * 4 + r;
            const float s1 = sq1_s[lrow];
            const size_t gbase = (size_t)(block_row + lrow) * M + block_col;
            #pragma unroll
            for (int j = 0; j < 4; ++j) {
                const int lcol = wc + j * 16 + lm;
                const float v = fmaf(-2.f, acc[i][j][r], s1 + sq2_s[lcol]);
                out[gbase + lcol] = fmaxf(v, 0.f);
            }
        }
    }
}

extern "C" void kernel_launch(void* const* d_in, const int* in_sizes, int n_in,
                              void* d_out, int out_size, void* d_ws, size_t ws_size,
                              hipStream_t stream) {
    const float* x1 = (const float*)d_in[0];
    const float* x2 = (const float*)d_in[1];
    float* out = (float*)d_out;
    const int N = in_sizes[0] / KD;   // 8192
    const int M = in_sizes[1] / KD;   // 8192

    dim3 grid(M / TILE, N / TILE);    // (64, 64)
    dim3 block(256);
    sqeuclid_mfma<<<grid, block, 0, stream>>>(x1, x2, out, M);
}